// Round 1
// baseline (539.530 us; speedup 1.0000x reference)
//
#include <hip/hip_runtime.h>
#include <math.h>

// Problem constants (fixed by the reference setup_inputs).
#define N 8192
#define D 64
#define C 100
#define T 30

static constexpr float D_LOG_2PI   = 117.62413225019811f; // D * log(2*pi)
static constexpr float EV_BUDGET_F = 80.992775903017304f; // 0.5 * D * log(4*pi)
static constexpr float LOG_EV_CLAMP_F = 10.0f;

// ---------------------------------------------------------------------------
// Kernel P: per-class precompute.
//   G[c][u][v] = z0[c,u,:] . z0[c,v,:]   (30x30 Gram per class)
//   alpha[c][t] = softplus(alpha_prime), beta[c][t] = -alpha + softplus(beta_prime)
// grid = C blocks, 256 threads.
// ---------------------------------------------------------------------------
__global__ void prep_kernel(const float* __restrict__ z0,
                            const float* __restrict__ ap,
                            const float* __restrict__ bp,
                            float* __restrict__ G,
                            float* __restrict__ alphas,
                            float* __restrict__ betas) {
    const int c = blockIdx.x;
    __shared__ float z0s[T * D];
    for (int i = threadIdx.x; i < T * D; i += blockDim.x)
        z0s[i] = z0[c * T * D + i];
    __syncthreads();

    for (int idx = threadIdx.x; idx < T * T; idx += blockDim.x) {
        const int u = idx / T, v = idx % T;
        float s = 0.0f;
        #pragma unroll
        for (int d = 0; d < D; ++d)
            s = fmaf(z0s[u * D + d], z0s[v * D + d], s);
        G[c * T * T + idx] = s;
    }

    if (threadIdx.x < T) {
        const float a = ap[c * T + threadIdx.x];
        const float b = bp[c * T + threadIdx.x];
        // numerically stable softplus
        const float spa = fmaxf(a, 0.0f) + log1pf(expf(-fabsf(a)));
        const float spb = fmaxf(b, 0.0f) + log1pf(expf(-fabsf(b)));
        alphas[c * T + threadIdx.x] = spa;
        betas[c * T + threadIdx.x]  = -spa + spb;
    }
}

// ---------------------------------------------------------------------------
// Kernel A: the flow, restructured via the Gram trick.
// One thread per (sample n, class c).  z_t is never materialized; we track
//   q = ||z_t||^2,  w[u] = z_t . z0[c,u]
// with scalar recurrences (flow is linear in z each step).
// grid = (N/256, C), 256 threads.  All shared operands (z0 row, G row,
// alpha/beta) are wave-uniform -> compiler scalarizes to s_load.
// ---------------------------------------------------------------------------
__global__ __launch_bounds__(256) void flow_kernel(
        const float* __restrict__ x,
        const float* __restrict__ z0,
        const float* __restrict__ G,
        const float* __restrict__ alphas,
        const float* __restrict__ betas,
        float* __restrict__ lp) {
    const int c = blockIdx.y;
    const int n = blockIdx.x * blockDim.x + threadIdx.x;

    const float* __restrict__ zc = z0 + (size_t)c * T * D;  // uniform
    const float* __restrict__ Gc = G  + (size_t)c * T * T;  // uniform
    const float* __restrict__ ac = alphas + c * T;          // uniform
    const float* __restrict__ bc = betas  + c * T;          // uniform

    // Load this sample's x row into registers (16x float4).
    float xv[D];
    const float4* xp = (const float4*)(x + (size_t)n * D);
    #pragma unroll
    for (int i = 0; i < D / 4; ++i) {
        float4 v = xp[i];
        xv[4 * i + 0] = v.x; xv[4 * i + 1] = v.y;
        xv[4 * i + 2] = v.z; xv[4 * i + 3] = v.w;
    }

    // q0 = ||x||^2
    float q = 0.0f;
    #pragma unroll
    for (int d = 0; d < D; ++d) q = fmaf(xv[d], xv[d], q);

    // w[u] = x . z0[c,u]  (dominant cost: 30*64 FMA; z0 via scalar loads)
    float w[T];
    #pragma unroll
    for (int u = 0; u < T; ++u) {
        float s = 0.0f;
        #pragma unroll
        for (int d = 0; d < D; ++d)
            s = fmaf(xv[d], zc[u * D + d], s);
        w[u] = s;
    }

    float ld = 0.0f;
    #pragma unroll
    for (int t = 0; t < T; ++t) {
        const float Gtt = Gc[t * T + t];
        float r2 = q - 2.0f * w[t] + Gtt;
        r2 = fmaxf(r2, 0.0f);
        const float r     = sqrtf(r2);
        const float alpha = ac[t];
        const float beta  = bc[t];
        const float h  = 1.0f / (alpha + r);
        const float bh = beta * h;
        const float f  = 1.0f + bh;
        // log|det| increment: (D-1)*log1p(bh) + log1p(bh*(1 - h*r))
        ld += (float)(D - 1) * log1pf(bh) + log1pf(bh * (1.0f - h * r));
        // q_{t+1} = f^2 q - 2 f bh w[t] + bh^2 Gtt   (uses OLD w[t])
        q = f * f * q - 2.0f * f * bh * w[t] + bh * bh * Gtt;
        // w_{t+1}[u] = f w[u] - bh G[t][u]  (only future u needed)
        #pragma unroll
        for (int u = t + 1; u < T; ++u)
            w[u] = fmaf(f, w[u], -bh * Gc[t * T + u]);
    }

    lp[(size_t)c * N + n] = -0.5f * (D_LOG_2PI + q) + ld;
}

// ---------------------------------------------------------------------------
// Kernel B: logits[n][c] = x[n] . W[:,c] + b[c].
// One block per sample (x row uniform -> s_load), lane c -> coalesced W reads.
// ---------------------------------------------------------------------------
__global__ void logits_kernel(const float* __restrict__ x,
                              const float* __restrict__ W,
                              const float* __restrict__ b,
                              float* __restrict__ logits) {
    const int n = blockIdx.x;
    const int c = threadIdx.x;
    if (c >= C) return;
    const float* __restrict__ xr = x + (size_t)n * D;  // uniform
    float s = b[c];
    #pragma unroll
    for (int d = 0; d < D; ++d)
        s = fmaf(xr[d], W[d * C + c], s);
    logits[(size_t)n * C + c] = s;
}

// ---------------------------------------------------------------------------
// Kernel C: epilogue. Per sample:
//   marg = logsumexp_c(lp[c][n] + log freq[c]);  class_lp = lp[label][n]
//   ev = exp(min(marg + EV_BUDGET, 10))
//   out[n][c] = log1p(ev * softmax(logits[n])[c]);  out[n][C] = class_lp
// ---------------------------------------------------------------------------
__global__ void epilogue_kernel(const float* __restrict__ lp,
                                const float* __restrict__ logits,
                                const int* __restrict__ labels,
                                const float* __restrict__ freq,
                                float* __restrict__ out) {
    const int n = blockIdx.x * blockDim.x + threadIdx.x;

    // online logsumexp over classes (branchless)
    float m = -INFINITY, s = 0.0f;
    for (int c = 0; c < C; ++c) {
        const float v = lp[(size_t)c * N + n] + __logf(freq[c]);
        const float m2 = fmaxf(m, v);
        s = s * __expf(m - m2) + __expf(v - m2);
        m = m2;
    }
    const float marg = m + __logf(s);
    const float log_ev = fminf(marg + EV_BUDGET_F, LOG_EV_CLAMP_F);
    const float ev = __expf(log_ev);

    const int lab = labels[n];
    const float class_lp = lp[(size_t)lab * N + n];

    // softmax over logits row (2 passes; row is L1/L2 resident)
    const float* __restrict__ lr = logits + (size_t)n * C;
    float lm = -INFINITY;
    for (int c = 0; c < C; ++c) lm = fmaxf(lm, lr[c]);
    float ls = 0.0f;
    for (int c = 0; c < C; ++c) ls += __expf(lr[c] - lm);
    const float inv = ev / ls;

    float* __restrict__ outr = out + (size_t)n * (C + 1);
    for (int c = 0; c < C; ++c)
        outr[c] = log1pf(__expf(lr[c] - lm) * inv);
    outr[C] = class_lp;
}

// ---------------------------------------------------------------------------
extern "C" void kernel_launch(void* const* d_in, const int* in_sizes, int n_in,
                              void* d_out, int out_size, void* d_ws, size_t ws_size,
                              hipStream_t stream) {
    const float* x      = (const float*)d_in[0];
    const int*   labels = (const int*)  d_in[1];
    const float* freq   = (const float*)d_in[2];
    const float* z0     = (const float*)d_in[3];
    const float* ap     = (const float*)d_in[4];
    const float* bp     = (const float*)d_in[5];
    const float* W      = (const float*)d_in[6];
    const float* b      = (const float*)d_in[7];
    float* out = (float*)d_out;

    // Workspace layout (floats): lp[C*N] | logits[N*C] | G[C*T*T] | alpha[C*T] | beta[C*T]
    float* ws     = (float*)d_ws;
    float* lp     = ws;
    float* logits = lp + (size_t)C * N;
    float* G      = logits + (size_t)N * C;
    float* alphas = G + (size_t)C * T * T;
    float* betas  = alphas + (size_t)C * T;

    prep_kernel<<<C, 256, 0, stream>>>(z0, ap, bp, G, alphas, betas);
    flow_kernel<<<dim3(N / 256, C), 256, 0, stream>>>(x, z0, G, alphas, betas, lp);
    logits_kernel<<<N, 128, 0, stream>>>(x, W, b, logits);
    epilogue_kernel<<<N / 64, 64, 0, stream>>>(lp, logits, labels, freq, out);
}

// Round 2
// 262.810 us; speedup vs baseline: 2.0529x; 2.0529x over previous
//
#include <hip/hip_runtime.h>
#include <math.h>

// Problem constants (fixed by the reference setup_inputs).
#define N 8192
#define D 64
#define C 100
#define T 30
#define GSTRIDE 32  // padded leading dim of per-class Gram rows

static constexpr float D_LOG_2PI      = 117.62413225019811f; // D * log(2*pi)
static constexpr float EV_BUDGET_F    = 80.992775903017304f; // 0.5 * D * log(4*pi)
static constexpr float LOG_EV_CLAMP_F = 10.0f;

// ---------------------------------------------------------------------------
// Kernel P: per-class precompute.
//   Gp[c][u][v] (v-stride 32) = z0[c,u,:] . z0[c,v,:]
//   alpha[c][t] = softplus(alpha_prime), beta[c][t] = -alpha + softplus(beta_prime)
// ---------------------------------------------------------------------------
__global__ void prep_kernel(const float* __restrict__ z0,
                            const float* __restrict__ ap,
                            const float* __restrict__ bp,
                            float* __restrict__ Gp,
                            float* __restrict__ alphas,
                            float* __restrict__ betas) {
    const int c = blockIdx.x;
    __shared__ float z0s[T * D];
    for (int i = threadIdx.x; i < T * D; i += blockDim.x)
        z0s[i] = z0[c * T * D + i];
    __syncthreads();

    for (int idx = threadIdx.x; idx < T * T; idx += blockDim.x) {
        const int u = idx / T, v = idx % T;
        float s = 0.0f;
        #pragma unroll
        for (int d = 0; d < D; ++d)
            s = fmaf(z0s[u * D + d], z0s[v * D + d], s);
        Gp[(size_t)c * T * GSTRIDE + u * GSTRIDE + v] = s;
    }

    if (threadIdx.x < T) {
        const float a = ap[c * T + threadIdx.x];
        const float b = bp[c * T + threadIdx.x];
        const float spa = fmaxf(a, 0.0f) + log1pf(expf(-fabsf(a)));
        const float spb = fmaxf(b, 0.0f) + log1pf(expf(-fabsf(b)));
        alphas[c * T + threadIdx.x] = spa;
        betas[c * T + threadIdx.x]  = -spa + spb;
    }
}

// ---------------------------------------------------------------------------
// Kernel A: flow via Gram trick, register-pressure-aware.
//   Phase 1: w[u] = x.z0[c,u], q = ||x||^2, accumulated in 4 chunks of 16
//            (live set ~ w[30]+xc[16], fits in VGPRs -> no AGPR spill remat).
//   Phase 2: scalar recurrence; log-det via running product + f^63 powering
//            (no libm log1p); scaled-w trick makes the w-update 1 FMA each.
// ---------------------------------------------------------------------------
__global__ __launch_bounds__(256, 4) void flow_kernel(
        const float* __restrict__ x,
        const float* __restrict__ z0,
        const float* __restrict__ Gp,
        const float* __restrict__ alphas,
        const float* __restrict__ betas,
        float* __restrict__ lp) {
    const int c = blockIdx.y;
    const int n = blockIdx.x * 256 + threadIdx.x;

    const float4* __restrict__ zc = (const float4*)(z0 + (size_t)c * T * D); // uniform
    const float*  __restrict__ Gc = Gp + (size_t)c * T * GSTRIDE;            // uniform
    const float*  __restrict__ ac = alphas + c * T;                          // uniform
    const float*  __restrict__ bc = betas  + c * T;                          // uniform
    const float4* __restrict__ xp = (const float4*)(x + (size_t)n * D);

    float w[T];
    #pragma unroll
    for (int u = 0; u < T; ++u) w[u] = 0.0f;
    float q = 0.0f;

    #pragma unroll
    for (int ch = 0; ch < 4; ++ch) {
        float xc[16];
        #pragma unroll
        for (int j = 0; j < 4; ++j) {
            const float4 v = xp[ch * 4 + j];
            xc[4 * j + 0] = v.x; xc[4 * j + 1] = v.y;
            xc[4 * j + 2] = v.z; xc[4 * j + 3] = v.w;
        }
        #pragma unroll
        for (int j = 0; j < 16; ++j) q = fmaf(xc[j], xc[j], q);
        #pragma unroll
        for (int u = 0; u < T; ++u) {
            #pragma unroll
            for (int j = 0; j < 4; ++j) {
                const float4 zv = zc[u * 16 + ch * 4 + j];  // uniform load
                w[u] = fmaf(xc[4 * j + 0], zv.x, w[u]);
                w[u] = fmaf(xc[4 * j + 1], zv.y, w[u]);
                w[u] = fmaf(xc[4 * j + 2], zv.z, w[u]);
                w[u] = fmaf(xc[4 * j + 3], zv.w, w[u]);
            }
        }
    }

    // Phase 2. Invariants: true w_t[u] = P * w[u]; q is the true ||z_t||^2.
    float P    = 1.0f;  // product of f's so far
    float prod = 1.0f;  // running product whose log is the log-det increment
    float ld   = 0.0f;
    #pragma unroll
    for (int t = 0; t < T; ++t) {
        const float Gtt   = Gc[t * GSTRIDE + t];
        const float alpha = ac[t];
        const float beta  = bc[t];
        const float wt    = P * w[t];
        float r2 = fmaf(-2.0f, wt, q) + Gtt;
        r2 = fmaxf(r2, 0.0f);
        const float r  = __builtin_amdgcn_sqrtf(r2);
        const float h  = __builtin_amdgcn_rcpf(alpha + r);
        const float bh = beta * h;
        const float f  = 1.0f + bh;
        // per-step det factor: f^63 * (1 + bh*(1-h*r)); note 1-h*r == alpha*h
        const float f2 = f * f, f4 = f2 * f2, f8 = f4 * f4;
        const float f16 = f8 * f8, f32v = f16 * f16;
        float p = f32v * f16; p *= f8; p *= f4; p *= f2; p *= f;  // f^63
        p *= fmaf(bh * alpha, h, 1.0f);
        prod *= p;
        if ((t % 6) == 5) { ld += __logf(prod); prod = 1.0f; }
        // q_{t+1} = f^2 q - 2 f bh wt + bh^2 Gtt  (old wt)
        const float m = bh * f;
        float qn = f2 * q;
        qn = fmaf(m, -2.0f * wt, qn);
        qn = fmaf(bh * bh, Gtt, qn);
        q = qn;
        // scaled-w update: w[u] -= (bh/(P f)) * G[t][u]
        const float Pn = P * f;
        const float k  = bh * __builtin_amdgcn_rcpf(Pn);
        #pragma unroll
        for (int u = t + 1; u < T; ++u)
            w[u] = fmaf(-k, Gc[t * GSTRIDE + u], w[u]);
        P = Pn;
    }
    ld += __logf(prod);  // leftover (log(1)=0 when T%6==0)

    lp[(size_t)c * N + n] = -0.5f * (D_LOG_2PI + q) + ld;
}

// ---------------------------------------------------------------------------
// Kernel B: logits[n][c] = x[n] . W[:,c] + b[c].
// ---------------------------------------------------------------------------
__global__ void logits_kernel(const float* __restrict__ x,
                              const float* __restrict__ W,
                              const float* __restrict__ b,
                              float* __restrict__ logits) {
    const int n = blockIdx.x;
    const int c = threadIdx.x;
    if (c >= C) return;
    const float* __restrict__ xr = x + (size_t)n * D;  // uniform
    float s = b[c];
    #pragma unroll
    for (int d = 0; d < D; ++d)
        s = fmaf(xr[d], W[d * C + c], s);
    logits[(size_t)n * C + c] = s;
}

// ---------------------------------------------------------------------------
// Kernel C: epilogue (unchanged from R1 — passed; revisit if it shows up hot).
// ---------------------------------------------------------------------------
__global__ void epilogue_kernel(const float* __restrict__ lp,
                                const float* __restrict__ logits,
                                const int* __restrict__ labels,
                                const float* __restrict__ freq,
                                float* __restrict__ out) {
    const int n = blockIdx.x * blockDim.x + threadIdx.x;

    float m = -INFINITY, s = 0.0f;
    for (int c = 0; c < C; ++c) {
        const float v = lp[(size_t)c * N + n] + __logf(freq[c]);
        const float m2 = fmaxf(m, v);
        s = s * __expf(m - m2) + __expf(v - m2);
        m = m2;
    }
    const float marg = m + __logf(s);
    const float log_ev = fminf(marg + EV_BUDGET_F, LOG_EV_CLAMP_F);
    const float ev = __expf(log_ev);

    const int lab = labels[n];
    const float class_lp = lp[(size_t)lab * N + n];

    const float* __restrict__ lr = logits + (size_t)n * C;
    float lm = -INFINITY;
    for (int c = 0; c < C; ++c) lm = fmaxf(lm, lr[c]);
    float ls = 0.0f;
    for (int c = 0; c < C; ++c) ls += __expf(lr[c] - lm);
    const float inv = ev / ls;

    float* __restrict__ outr = out + (size_t)n * (C + 1);
    for (int c = 0; c < C; ++c)
        outr[c] = log1pf(__expf(lr[c] - lm) * inv);
    outr[C] = class_lp;
}

// ---------------------------------------------------------------------------
extern "C" void kernel_launch(void* const* d_in, const int* in_sizes, int n_in,
                              void* d_out, int out_size, void* d_ws, size_t ws_size,
                              hipStream_t stream) {
    const float* x      = (const float*)d_in[0];
    const int*   labels = (const int*)  d_in[1];
    const float* freq   = (const float*)d_in[2];
    const float* z0     = (const float*)d_in[3];
    const float* ap     = (const float*)d_in[4];
    const float* bp     = (const float*)d_in[5];
    const float* W      = (const float*)d_in[6];
    const float* b      = (const float*)d_in[7];
    float* out = (float*)d_out;

    // Workspace (floats): lp[C*N] | logits[N*C] | Gp[C*T*32] | alpha[C*T] | beta[C*T]
    float* ws     = (float*)d_ws;
    float* lp     = ws;
    float* logits = lp + (size_t)C * N;
    float* Gp     = logits + (size_t)N * C;
    float* alphas = Gp + (size_t)C * T * GSTRIDE;
    float* betas  = alphas + (size_t)C * T;

    prep_kernel<<<C, 256, 0, stream>>>(z0, ap, bp, Gp, alphas, betas);
    flow_kernel<<<dim3(N / 256, C), 256, 0, stream>>>(x, z0, Gp, alphas, betas, lp);
    logits_kernel<<<N, 128, 0, stream>>>(x, W, b, logits);
    epilogue_kernel<<<N / 64, 64, 0, stream>>>(lp, logits, labels, freq, out);
}

// Round 3
// 160.051 us; speedup vs baseline: 3.3710x; 1.6420x over previous
//
#include <hip/hip_runtime.h>
#include <math.h>

// Problem constants (fixed by the reference setup_inputs).
#define N 8192
#define D 64
#define C 100
#define T 30
#define GSTRIDE 32   // padded leading dim of per-class Gram rows
#define ZROWS 32     // z0 rows padded 30 -> 32 for MFMA u-tiles
#define WSTRIDE 36   // wlds row stride (floats): 16B-aligned, non-pow2 banks

static constexpr float D_LOG_2PI      = 117.62413225019811f; // D * log(2*pi)
static constexpr float EV_BUDGET_F    = 80.992775903017304f; // 0.5 * D * log(4*pi)
static constexpr float LOG_EV_CLAMP_F = 10.0f;

typedef __attribute__((ext_vector_type(8))) short short8x;   // 8 x bf16 bits (4 VGPRs)
typedef __attribute__((ext_vector_type(4))) float floatx4;   // MFMA C/D frag

static __device__ __forceinline__ unsigned short f2bf(float f) {
    __bf16 h = (__bf16)f;                       // RNE convert
    return __builtin_bit_cast(unsigned short, h);
}

// ---------------------------------------------------------------------------
// Kernel P: per-class precompute.
//   Gp[c][u][v] (v-stride 32) = z0[c,u,:] . z0[c,v,:]
//   alpha/beta via softplus; z0bf[c][32][64] = bf16(z0), rows 30,31 zeroed.
// ---------------------------------------------------------------------------
__global__ void prep_kernel(const float* __restrict__ z0,
                            const float* __restrict__ ap,
                            const float* __restrict__ bp,
                            float* __restrict__ Gp,
                            float* __restrict__ alphas,
                            float* __restrict__ betas,
                            unsigned short* __restrict__ z0bf) {
    const int c = blockIdx.x;
    __shared__ float z0s[T * D];
    for (int i = threadIdx.x; i < T * D; i += blockDim.x)
        z0s[i] = z0[c * T * D + i];
    __syncthreads();

    for (int idx = threadIdx.x; idx < T * T; idx += blockDim.x) {
        const int u = idx / T, v = idx % T;
        float s = 0.0f;
        #pragma unroll
        for (int d = 0; d < D; ++d)
            s = fmaf(z0s[u * D + d], z0s[v * D + d], s);
        Gp[(size_t)c * T * GSTRIDE + u * GSTRIDE + v] = s;
    }

    // bf16 pack, padded to 32 rows (zeros -> w[30],w[31]=0, unused)
    for (int i = threadIdx.x; i < ZROWS * D; i += blockDim.x) {
        const int u = i >> 6;
        z0bf[(size_t)c * ZROWS * D + i] = f2bf(u < T ? z0s[u * D + (i & 63)] : 0.0f);
    }

    if (threadIdx.x < T) {
        const float a = ap[c * T + threadIdx.x];
        const float b = bp[c * T + threadIdx.x];
        const float spa = fmaxf(a, 0.0f) + log1pf(expf(-fabsf(a)));
        const float spb = fmaxf(b, 0.0f) + log1pf(expf(-fabsf(b)));
        alphas[c * T + threadIdx.x] = spa;
        betas[c * T + threadIdx.x]  = -spa + spb;
    }
}

// ---------------------------------------------------------------------------
// Kernel A: flow. Phase 1 = MFMA (W-tile [32u x 64n] per wave = 16 mfma),
// LDS transpose so each thread owns its sample's w[0..29]; Phase 2 = the
// verified scalar recurrence (Gram trick, f^63 product log-det).
// ---------------------------------------------------------------------------
__global__ __launch_bounds__(256, 4) void flow_kernel(
        const float* __restrict__ x,
        const unsigned short* __restrict__ z0bf,
        const float* __restrict__ Gp,
        const float* __restrict__ alphas,
        const float* __restrict__ betas,
        float* __restrict__ lp) {
    const int c    = blockIdx.y;
    const int wv   = threadIdx.x >> 6;
    const int ln   = threadIdx.x & 63;
    const int col  = ln & 15;
    const int quad = ln >> 4;
    const int nb   = blockIdx.x * 256 + wv * 64;  // wave's 64-sample base
    const int n    = nb + ln;                     // this thread's sample

    __shared__ float wlds[4][64 * WSTRIDE];       // 36,864 B

    const float* __restrict__ Gc = Gp + (size_t)c * T * GSTRIDE;  // uniform
    const float* __restrict__ ac = alphas + c * T;                // uniform
    const float* __restrict__ bc = betas  + c * T;                // uniform

    // ---- Phase 1: w[u][n] = sum_d z0[c,u,d] * x[n,d] via MFMA ----
    // A frag: lane holds A[m=col][k=quad*8+j]  (A = z0 rows)
    const unsigned short* zb = z0bf + (size_t)c * ZROWS * D;
    short8x A[2][2];
    #pragma unroll
    for (int mu = 0; mu < 2; ++mu)
        #pragma unroll
        for (int kc = 0; kc < 2; ++kc)
            A[mu][kc] = *(const short8x*)(zb + (mu * 16 + col) * D + kc * 32 + quad * 8);

    floatx4 acc[2][4];
    #pragma unroll
    for (int mu = 0; mu < 2; ++mu)
        #pragma unroll
        for (int nt = 0; nt < 4; ++nt)
            acc[mu][nt] = (floatx4)(0.0f);

    #pragma unroll
    for (int nt = 0; nt < 4; ++nt) {
        #pragma unroll
        for (int kc = 0; kc < 2; ++kc) {
            // B frag: lane holds B[k=quad*8+j][n=col]; built from global fp32 x
            const float* bptr = x + (size_t)(nb + nt * 16 + col) * D + kc * 32 + quad * 8;
            const float4 f0 = ((const float4*)bptr)[0];
            const float4 f1 = ((const float4*)bptr)[1];
            short8x B;
            B[0] = f2bf(f0.x); B[1] = f2bf(f0.y); B[2] = f2bf(f0.z); B[3] = f2bf(f0.w);
            B[4] = f2bf(f1.x); B[5] = f2bf(f1.y); B[6] = f2bf(f1.z); B[7] = f2bf(f1.w);
            acc[0][nt] = __builtin_amdgcn_mfma_f32_16x16x32_bf16(A[0][kc], B, acc[0][nt], 0, 0, 0);
            acc[1][nt] = __builtin_amdgcn_mfma_f32_16x16x32_bf16(A[1][kc], B, acc[1][nt], 0, 0, 0);
        }
    }

    // q0 = ||x_n||^2 in fp32 (precision-critical; own-row loads, L2-resident)
    float q = 0.0f;
    {
        const float4* xq = (const float4*)(x + (size_t)n * D);
        #pragma unroll
        for (int i = 0; i < 16; ++i) {
            const float4 v = xq[i];
            q = fmaf(v.x, v.x, q); q = fmaf(v.y, v.y, q);
            q = fmaf(v.z, v.z, q); q = fmaf(v.w, v.w, q);
        }
    }

    // ---- LDS transpose: D-frag (col=n, row=u=quad*4+reg) -> per-thread w ----
    #pragma unroll
    for (int mu = 0; mu < 2; ++mu)
        #pragma unroll
        for (int nt = 0; nt < 4; ++nt) {
            const int r  = nt * 16 + col;          // sample within wave
            const int u0 = mu * 16 + quad * 4;     // first of 4 u's in frag
            *(floatx4*)&wlds[wv][r * WSTRIDE + u0] = acc[mu][nt];
        }
    __syncthreads();   // same-wave dependency only, but keep it safe/cheap

    float w[ZROWS];
    #pragma unroll
    for (int j = 0; j < 8; ++j) {
        const float4 t = *(const float4*)&wlds[wv][ln * WSTRIDE + j * 4];
        w[4 * j + 0] = t.x; w[4 * j + 1] = t.y;
        w[4 * j + 2] = t.z; w[4 * j + 3] = t.w;
    }

    // ---- Phase 2 (verified in R2): true w_t[u] = P*w[u]; q = ||z_t||^2 ----
    float P    = 1.0f;
    float prod = 1.0f;
    float ld   = 0.0f;
    #pragma unroll
    for (int t = 0; t < T; ++t) {
        const float Gtt   = Gc[t * GSTRIDE + t];
        const float alpha = ac[t];
        const float beta  = bc[t];
        const float wt    = P * w[t];
        float r2 = fmaf(-2.0f, wt, q) + Gtt;
        r2 = fmaxf(r2, 0.0f);
        const float r  = __builtin_amdgcn_sqrtf(r2);
        const float h  = __builtin_amdgcn_rcpf(alpha + r);
        const float bh = beta * h;
        const float f  = 1.0f + bh;
        // det factor: f^63 * (1 + bh*alpha*h);  (1 - h*r == alpha*h)
        const float f2 = f * f, f4 = f2 * f2, f8 = f4 * f4;
        const float f16 = f8 * f8, f32v = f16 * f16;
        float p = f32v * f16; p *= f8; p *= f4; p *= f2; p *= f;  // f^63
        p *= fmaf(bh * alpha, h, 1.0f);
        prod *= p;
        if ((t % 6) == 5) { ld += __logf(prod); prod = 1.0f; }
        // q_{t+1} = f^2 q - 2 f bh wt + bh^2 Gtt
        const float m = bh * f;
        float qn = f2 * q;
        qn = fmaf(m, -2.0f * wt, qn);
        qn = fmaf(bh * bh, Gtt, qn);
        q = qn;
        // scaled-w update: w[u] -= (bh/(P f)) * G[t][u]
        const float Pn = P * f;
        const float k  = bh * __builtin_amdgcn_rcpf(Pn);
        #pragma unroll
        for (int u = t + 1; u < T; ++u)
            w[u] = fmaf(-k, Gc[t * GSTRIDE + u], w[u]);
        P = Pn;
    }
    ld += __logf(prod);

    lp[(size_t)c * N + n] = -0.5f * (D_LOG_2PI + q) + ld;
}

// ---------------------------------------------------------------------------
// Kernel C: epilogue with fused logits. One block (128 thr) per sample;
// lane = class. Block reductions via 64-wide shuffles + 2-wave LDS combine.
// ---------------------------------------------------------------------------
__global__ __launch_bounds__(128) void epilogue_kernel(
        const float* __restrict__ lp,
        const float* __restrict__ x,
        const float* __restrict__ W,
        const float* __restrict__ b,
        const int* __restrict__ labels,
        const float* __restrict__ freq,
        float* __restrict__ out) {
    const int n  = blockIdx.x;
    const int c  = threadIdx.x;
    const int wv = c >> 6, ln = c & 63;
    __shared__ float red[2];

    float v  = -INFINITY;   // lp + log freq
    float lg = -INFINITY;   // logit
    if (c < C) {
        v = lp[(size_t)c * N + n] + __logf(freq[c]);
        const float* __restrict__ xr = x + (size_t)n * D;  // uniform -> s_load
        float s = b[c];
        #pragma unroll
        for (int d = 0; d < D; ++d)
            s = fmaf(xr[d], W[d * C + c], s);               // coalesced
        lg = s;
    }

    // logsumexp over classes
    float m = v;
    #pragma unroll
    for (int off = 32; off >= 1; off >>= 1) m = fmaxf(m, __shfl_xor(m, off));
    if (ln == 0) red[wv] = m;
    __syncthreads();
    m = fmaxf(red[0], red[1]);
    __syncthreads();
    const float e = __expf(v - m);   // -inf lanes -> 0
    float s = e;
    #pragma unroll
    for (int off = 32; off >= 1; off >>= 1) s += __shfl_xor(s, off);
    if (ln == 0) red[wv] = s;
    __syncthreads();
    s = red[0] + red[1];
    __syncthreads();
    const float marg = m + __logf(s);
    const float ev = __expf(fminf(marg + EV_BUDGET_F, LOG_EV_CLAMP_F));

    // softmax denom over logits
    float lm = lg;
    #pragma unroll
    for (int off = 32; off >= 1; off >>= 1) lm = fmaxf(lm, __shfl_xor(lm, off));
    if (ln == 0) red[wv] = lm;
    __syncthreads();
    lm = fmaxf(red[0], red[1]);
    __syncthreads();
    const float le = __expf(lg - lm);
    float ls = le;
    #pragma unroll
    for (int off = 32; off >= 1; off >>= 1) ls += __shfl_xor(ls, off);
    if (ln == 0) red[wv] = ls;
    __syncthreads();
    ls = red[0] + red[1];

    if (c < C)
        out[(size_t)n * (C + 1) + c] = log1pf(ev * le / ls);
    if (c == 0)
        out[(size_t)n * (C + 1) + C] = lp[(size_t)labels[n] * N + n];
}

// ---------------------------------------------------------------------------
extern "C" void kernel_launch(void* const* d_in, const int* in_sizes, int n_in,
                              void* d_out, int out_size, void* d_ws, size_t ws_size,
                              hipStream_t stream) {
    const float* x      = (const float*)d_in[0];
    const int*   labels = (const int*)  d_in[1];
    const float* freq   = (const float*)d_in[2];
    const float* z0     = (const float*)d_in[3];
    const float* ap     = (const float*)d_in[4];
    const float* bp     = (const float*)d_in[5];
    const float* W      = (const float*)d_in[6];
    const float* b      = (const float*)d_in[7];
    float* out = (float*)d_out;

    // Workspace (floats): lp[C*N] | Gp[C*T*32] | alpha[C*T] | beta[C*T] | z0bf
    float* ws     = (float*)d_ws;
    float* lp     = ws;
    float* Gp     = lp + (size_t)C * N;
    float* alphas = Gp + (size_t)C * T * GSTRIDE;
    float* betas  = alphas + (size_t)C * T;
    unsigned short* z0bf = (unsigned short*)(betas + (size_t)C * T);  // 16B-aligned

    prep_kernel<<<C, 256, 0, stream>>>(z0, ap, bp, Gp, alphas, betas, z0bf);
    flow_kernel<<<dim3(N / 256, C), 256, 0, stream>>>(x, z0bf, Gp, alphas, betas, lp);
    epilogue_kernel<<<N, 128, 0, stream>>>(lp, x, W, b, labels, freq, out);
}